// Round 1
// baseline (128.773 us; speedup 1.0000x reference)
//
#include <hip/hip_runtime.h>
#include <math.h>

#define Bq 4
#define Hh 16
#define Lq 1024
#define Dd 64
#define Kk 8
#define QT 128        // q rows per block (32 per wave PAIR, 4 pairs)
#define KT 128        // k rows per iteration; wave pair splits the 2 sub-tiles
#define SRk 72        // K LDS row stride (bf16 elems)
#define SRv 136       // V^T LDS row stride (128 cols + pad)
#define TB 1152       // bias table entries per copy (4 shifted copies)
#define FMAX 8.0f     // fixed softmax shift (verified safe R1-R9)
#define LOG2E 1.44269504f

#define KSZ (KT * SRk * 2)              // 18432 B
#define VSZ (Dd * SRv * 2)              // 17408 B
#define BOFF (KSZ + VSZ)                // 35840 B
#define SMEM_BYTES (BOFF + 4 * TB * 4)  // 54272 B -> 2 blocks/CU, 16 waves/CU

typedef __attribute__((ext_vector_type(8))) short short8;         // 8 bf16
typedef __attribute__((ext_vector_type(4))) unsigned int u32x4;   // 4 dwords
typedef __attribute__((ext_vector_type(16))) float f32x16;

// packed f32x2 -> bf16x2, round-half-up — BIT-IDENTICAL to R5's f2bh
// ((u+0x8000)>>16) but 3 VALU ops/pair via v_perm_b32 byte select.
// R9 post-mortem: __float22bfloat162_rn + reinterpret_cast took a local's
// address -> un-promoted alloca -> ~110 MB scratch traffic. Pure int ops only.
__device__ __forceinline__ unsigned int pk2(float a, float b) {
    return __builtin_amdgcn_perm(__float_as_uint(b) + 0x8000u,
                                 __float_as_uint(a) + 0x8000u,
                                 0x07060302u);
}

// j-permutation (verified R4-R9): V row j -> column slot so the S^T C/D
// register layout IS the PV A-fragment layout (P never touches LDS).
__device__ __forceinline__ int jperm(int j) {
    return (j & 32) | ((j & 8) << 1) | ((j & 4) << 1) | ((j & 16) >> 2) | (j & 3);
}

// ---------------------------------------------------------------------------
// R10: split-s occupancy doubling.  Block = 512 (8 waves), grid = (64, 8).
// Wave w = (qw = w>>1, sw = w&1): 32 q rows (32*qw..), k sub-tile sw only.
// Per-CU: 2 blocks x 8 waves = 16 waves = 4 waves/SIMD (was 2) — the kernel
// is latency-bound (all pipes <25% busy), so double the latency hiding.
// Epilogue: wave pair exchanges the O-half it does NOT store (+ l partial)
// through LDS (reused as scratch), sums, normalizes, stores its half.
// mfma_f32_32x32x16_bf16.  S^T = K Q^T, C/D: col=lane&31 (=i q-row),
// row=(r&3)+8*(r>>2)+4*(lane>>5) (=j_loc).  O = P V via jperm trick.
// Fixed-max softmax: p = exp2(S + (bias-FMAX)*log2e), Q pre-scaled 0.125*log2e.
// __launch_bounds__(512,2): same 128-VGPR cap as known-good (256,2) config
// (R6/R7: arg=4 capped VGPRs at 64 -> ~700 MB scratch spills. Never again.)
// ---------------------------------------------------------------------------
__global__ __launch_bounds__(512, 2) void attn_kernel(
    const float* __restrict__ qp, const float* __restrict__ kp,
    const float* __restrict__ vp,
    const float* __restrict__ off, const float* __restrict__ amp,
    const float* __restrict__ sh, const float* __restrict__ bpar,
    float* __restrict__ out)
{
    __shared__ __align__(16) char smem[SMEM_BYTES];
    short* k_s   = (short*)smem;             // [128][SRk] K rows [j][d]
    short* v_s   = (short*)(smem + KSZ);     // [64][SRv]  V^T [d][slot^swz]
    float* bias4 = (float*)(smem + BOFF);    // 4 shifted copies

    const int bh = blockIdx.x;            // fastest -> XCD = bh%8
    const int qs = blockIdx.y * QT;
    const int t  = threadIdx.x;
    const int w  = t >> 6;                // 0..7
    const int qw = w >> 1;                // q sub-block 0..3
    const int sw = w & 1;                 // k sub-tile 0/1
    const int lane = t & 63;
    const int l31 = lane & 31;
    const int h5  = lane >> 5;
    const int h   = bh & 15;

    // ---- bias copy 0: (log(ksum+eps+bp) - |rel|*slope - FMAX)*log2e ----
    float slope = (h < Hh - 2) ? 4.605170185988092f * exp2f(-6.0f * (float)h / 13.0f) : 0.0f;
    #pragma unroll
    for (int it = 0; it < 3; ++it) {
        int i = it * 512 + t;
        if (i < TB - 1) {
            float rel = (float)(i - 127 - qs);
            float ksum = 0.0f;
            #pragma unroll
            for (int kk = 0; kk < Kk; ++kk) {
                float a = amp[kk * Hh + h];
                float o = off[kk * Hh + h];
                float s = sh[kk * Hh + h];
                float sgn = (a > 0.0f) ? 1.0f : ((a < 0.0f) ? -1.0f : 0.0f);
                ksum += fabsf(a) / (1.0f + __expf(-sgn * (rel - o) / s));
            }
            bias4[i] = (logf(ksum + 1e-8f + bpar[h]) - fabsf(rel) * slope - FMAX) * LOG2E;
        }
    }

    // ---- Q B-frags (global, once), scale folded, packed converts ----
    const float QS = 0.125f * LOG2E;
    short8 bq[4];
    const float* qrow = qp + ((size_t)bh * Lq + qs + 32 * qw + l31) * Dd;
    #pragma unroll
    for (int c = 0; c < 4; ++c) {
        float4 x0 = *(const float4*)(qrow + c * 16 + h5 * 8);
        float4 x1 = *(const float4*)(qrow + c * 16 + h5 * 8 + 4);
        u32x4 a;
        a[0] = pk2(x0.x * QS, x0.y * QS);
        a[1] = pk2(x0.z * QS, x0.w * QS);
        a[2] = pk2(x1.x * QS, x1.y * QS);
        a[3] = pk2(x1.z * QS, x1.w * QS);
        bq[c] = __builtin_bit_cast(short8, a);
    }

    // ---- staging geometry: 512 threads cover the full 128-row tile once:
    // thread owns 4 consecutive rows x 4 cols (half the regs of the R5 scheme)
    const int g  = t >> 4;                // 0..31
    const int cl = t & 15;
    const int c4 = 4 * cl;
    const int jrow = 4 * g;               // tile row 0..124
    const int vcb = 64 * (g >> 4) + jperm(jrow & 63);
    const float* kbase = kp + (size_t)bh * Lq * Dd;
    const float* vbase = vp + (size_t)bh * Lq * Dd;

    // ---- prefetch iteration 0 ----
    float4 kr[4], vr[4];
    #pragma unroll
    for (int u = 0; u < 4; ++u) {
        kr[u] = *(const float4*)(kbase + (size_t)(jrow + u) * Dd + c4);
        vr[u] = *(const float4*)(vbase + (size_t)(jrow + u) * Dd + c4);
    }

    __syncthreads();                      // bias copy0 visible

    // ---- replicate bias copies 1..3 (copyP[i] = bias(i+P)) ----
    #pragma unroll
    for (int it = 0; it < 3; ++it) {
        int i = it * 512 + t;
        if (i < TB) {
            float b1 = bias4[i + 1 <= TB - 2 ? i + 1 : TB - 2];
            float b2 = bias4[i + 2 <= TB - 2 ? i + 2 : TB - 2];
            float b3 = bias4[i + 3 <= TB - 2 ? i + 3 : TB - 2];
            bias4[TB + i]     = b1;
            bias4[2 * TB + i] = b2;
            bias4[3 * TB + i] = b3;
        }
    }
    // ---- write tile 0: K row-major; V reg-transposed 4x4; packed converts --
    #pragma unroll
    for (int u = 0; u < 4; ++u) {
        uint2 kv;
        kv.x = pk2(kr[u].x, kr[u].y);
        kv.y = pk2(kr[u].z, kr[u].w);
        *(uint2*)&k_s[(jrow + u) * SRk + c4] = kv;
    }
    #pragma unroll
    for (int cc = 0; cc < 4; ++cc) {
        int d = c4 + cc;
        uint2 vv;
        vv.x = pk2(((const float*)&vr[0])[cc], ((const float*)&vr[1])[cc]);
        vv.y = pk2(((const float*)&vr[2])[cc], ((const float*)&vr[3])[cc]);
        *(uint2*)&v_s[d * SRv + (vcb ^ (8 * ((d >> 3) & 7)))] = vv;
    }
    __syncthreads();

    // ---- accumulators (partial over this wave's k sub-tiles) ----
    f32x16 O0, O1;
    #pragma unroll
    for (int r = 0; r < 16; ++r) { O0[r] = 0.f; O1[r] = 0.f; }
    float l_part = 0.0f;

    const int L0 = 4 * h5 - 32 * qw - l31 + 127;  // bias lane offset
    const int phi = L0 & 3;
    const float* bcopy = bias4 + phi * TB - phi;  // aligned-float4 view

    #pragma unroll 1
    for (int kt = 0; kt < Lq / KT; ++kt) {        // 8 iterations
        const int ks = kt * KT;

        // prefetch next iteration (VMEM overlaps compute below)
        if (kt < 7) {
            const float* kn = kbase + (size_t)(ks + KT) * Dd;
            const float* vn = vbase + (size_t)(ks + KT) * Dd;
            #pragma unroll
            for (int u = 0; u < 4; ++u) {
                kr[u] = *(const float4*)(kn + (size_t)(jrow + u) * Dd + c4);
                vr[u] = *(const float4*)(vn + (size_t)(jrow + u) * Dd + c4);
            }
        }

        // ---- S^T = K Q^T (this wave's sub-tile sw) ----
        f32x16 S0, S1;
        #pragma unroll
        for (int r = 0; r < 16; ++r) { S0[r] = 0.f; S1[r] = 0.f; }
        #pragma unroll
        for (int c = 0; c < 4; ++c) {
            short8 ak0 = *(const short8*)&k_s[(64 * sw + l31) * SRk + c * 16 + h5 * 8];
            S0 = __builtin_amdgcn_mfma_f32_32x32x16_bf16(ak0, bq[c], S0, 0, 0, 0);
        }
        #pragma unroll
        for (int c = 0; c < 4; ++c) {
            short8 ak1 = *(const short8*)&k_s[(64 * sw + 32 + l31) * SRk + c * 16 + h5 * 8];
            S1 = __builtin_amdgcn_mfma_f32_32x32x16_bf16(ak1, bq[c], S1, 0, 0, 0);
        }

        // ---- softmax: p = exp2(S + bias') ----
        float lsum = 0.0f;
        #pragma unroll
        for (int p = 0; p < 4; ++p) {
            int base0 = ks + 64 * sw + 8 * p + L0;
            float4 b0 = *(const float4*)(bcopy + base0);
            float4 b1 = *(const float4*)(bcopy + base0 + 32);
            #pragma unroll
            for (int q = 0; q < 4; ++q) {
                int r = 4 * p + q;
                float bq0 = (q == 0) ? b0.x : (q == 1) ? b0.y : (q == 2) ? b0.z : b0.w;
                float bq1 = (q == 0) ? b1.x : (q == 1) ? b1.y : (q == 2) ? b1.z : b1.w;
                float e0 = __builtin_amdgcn_exp2f(S0[r] + bq0);
                float e1 = __builtin_amdgcn_exp2f(S1[r] + bq1);
                S0[r] = e0; S1[r] = e1;
                lsum += e0 + e1;
            }
        }
        l_part += lsum;

        // ---- P A-frags in-register (jperm trick), packed converts ----
        short8 ap[4];
        #pragma unroll
        for (int c = 0; c < 4; ++c) {
            int b = (c & 1) * 4;
            u32x4 a;
            if (c >> 1) {
                a[0] = pk2(S1[b + 0], S1[b + 1]);
                a[1] = pk2(S1[b + 2], S1[b + 3]);
                a[2] = pk2(S1[b + 8], S1[b + 9]);
                a[3] = pk2(S1[b + 10], S1[b + 11]);
            } else {
                a[0] = pk2(S0[b + 0], S0[b + 1]);
                a[1] = pk2(S0[b + 2], S0[b + 3]);
                a[2] = pk2(S0[b + 8], S0[b + 9]);
                a[3] = pk2(S0[b + 10], S0[b + 11]);
            }
            ap[c] = __builtin_bit_cast(short8, a);
        }

        // ---- O += P V (sub-tile sw) ----
        #pragma unroll
        for (int nb = 0; nb < 2; ++nb) {
            int d = nb * 32 + l31;
            int swz = 8 * ((d >> 3) & 7);
            f32x16 acc = nb ? O1 : O0;
            #pragma unroll
            for (int c = 0; c < 4; ++c) {
                short8 bv = *(const short8*)&v_s[d * SRv + 64 * sw + ((c * 16 + h5 * 8) ^ swz)];
                acc = __builtin_amdgcn_mfma_f32_32x32x16_bf16(ap[c], bv, acc, 0, 0, 0);
            }
            if (nb) O1 = acc; else O0 = acc;
        }

        __syncthreads();                  // all waves done reading k_s/v_s
        if (kt < 7) {
            #pragma unroll
            for (int u = 0; u < 4; ++u) {
                uint2 kv;
                kv.x = pk2(kr[u].x, kr[u].y);
                kv.y = pk2(kr[u].z, kr[u].w);
                *(uint2*)&k_s[(jrow + u) * SRk + c4] = kv;
            }
            #pragma unroll
            for (int cc = 0; cc < 4; ++cc) {
                int d = c4 + cc;
                uint2 vv;
                vv.x = pk2(((const float*)&vr[0])[cc], ((const float*)&vr[1])[cc]);
                vv.y = pk2(((const float*)&vr[2])[cc], ((const float*)&vr[3])[cc]);
                *(uint2*)&v_s[d * SRv + (vcb ^ (8 * ((d >> 3) & 7)))] = vv;
            }
        }
        __syncthreads();
    }

    // ---- epilogue: wave pair (qw,0)+(qw,1) combine, normalize, store ----
    // Each wave writes the O-half it does NOT store (+ its l partial) into
    // LDS scratch (k_s/v_s region is dead — all waves passed the final
    // barrier after their last LDS reads), reads the partner's, sums.
    // Scratch: 8 regions x 64 lanes x 17 floats, lane stride 17 dwords
    // (odd -> 2-way bank alias only, free).
    l_part += __shfl_xor(l_part, 32);     // combine j-halves within wave
    float* red = (float*)smem;
    const int rb = (w * 64 + lane) * 17;
    #pragma unroll
    for (int r = 0; r < 16; ++r) red[rb + r] = sw ? O0[r] : O1[r];
    red[rb + 16] = l_part;
    __syncthreads();
    const int pb = ((w ^ 1) * 64 + lane) * 17;
    float inv = 1.0f / (l_part + red[pb + 16]);
    float* ob = out + ((size_t)bh * Lq + qs + 32 * qw) * Dd;
    #pragma unroll
    for (int r = 0; r < 16; ++r) {
        float o = (sw ? O1[r] : O0[r]) + red[pb + r];
        int rowp = (r & 3) + 8 * (r >> 2) + 4 * h5;
        float invp = __shfl(inv, rowp, 32);   // l lives at lane l31==row
        ob[(size_t)rowp * Dd + 32 * sw + l31] = o * invp;  // sw picks col half
    }
}

extern "C" void kernel_launch(void* const* d_in, const int* in_sizes, int n_in,
                              void* d_out, int out_size, void* d_ws, size_t ws_size,
                              hipStream_t stream) {
    const float* q   = (const float*)d_in[0];
    const float* k   = (const float*)d_in[1];
    const float* v   = (const float*)d_in[2];
    const float* off = (const float*)d_in[3];
    const float* amp = (const float*)d_in[4];
    const float* sh  = (const float*)d_in[5];
    const float* bp  = (const float*)d_in[6];
    float* out = (float*)d_out;

    dim3 grid(Bq * Hh, Lq / QT);          // (64, 8), bh fastest -> XCD locality
    attn_kernel<<<grid, 512, 0, stream>>>(q, k, v, off, amp, sh, bp, out);
}